// Round 10
// baseline (59.377 us; speedup 1.0000x reference)
//
#include <hip/hip_runtime.h>

#define CC   14      // num labels
#define MAXT 13      // max trials
#define TPB  256
#define RAMP_CAP 1.8f

// harmonic numbers, fp32 chain in reference cumsum order
constexpr float H2  = 1.0f + 0.5f;
constexpr float H3  = H2  + (1.0f/3.0f);
constexpr float H4  = H3  + 0.25f;
constexpr float H5  = H4  + 0.2f;
constexpr float H6  = H5  + (1.0f/6.0f);
constexpr float H7  = H6  + (1.0f/7.0f);
constexpr float H14 = H7 + 0.125f + (1.0f/9.0f) + 0.1f + (1.0f/11.0f)
                         + (1.0f/12.0f) + (1.0f/13.0f) + (1.0f/14.0f);

// 4B-aligned vector types: legal on gfx9; a 16B load at float index 13*j
// (byte 52*j) never crosses a 128B line (52j mod 128 <= 112 for j in 0..13).
typedef float float4u __attribute__((ext_vector_type(4), aligned(4)));
typedef float float2u __attribute__((ext_vector_type(2), aligned(4)));
typedef int   int4u   __attribute__((ext_vector_type(4), aligned(4)));
typedef int   int2u   __attribute__((ext_vector_type(2), aligned(4)));

// One positive label: one float4 = trials 0..3 (99.67% resolve);
// tail trials 4..12 is a ~0.3% scalar path, gated by gm!=0 (resolvable).
template<int J>
__device__ __forceinline__ void do_label(unsigned pm, int nn, float fnn,
                                         const float* __restrict__ rowF,
                                         const float (&x)[CC], float& lw)
{
    if ((pm >> J) & 1u) {
        const float4u q = *(const float4u*)(rowF + 13 * J);
        const float e[4] = {q.x, q.y, q.z, q.w};

        // one pass over row: neg_sum + resolving-negative bitmask (k-order)
        const float m1 = 1.0f - x[J];
        float nsum = 0.f; unsigned gm = 0; int cnt = 0;
        #pragma unroll
        for (int k = 0; k < CC; ++k) {
            if (!((pm >> k) & 1u)) {
                nsum += fminf(fmaxf(x[J] - x[k], 0.f), RAMP_CAP);
                if (m1 + x[k] >= 0.f) gm |= (1u << cnt);   // ref association
                ++cnt;
            }
        }

        unsigned bits = 0;
        #pragma unroll
        for (int t = 0; t < 4; ++t) {
            int ti = (int)(e[t] * fnn);           // trunc == astype(int32)
            ti = ti < 0 ? 0 : ti;
            ti = ti > nn - 1 ? nn - 1 : ti;
            bits |= ((gm >> ti) & 1u) << t;
        }
        if (bits == 0u && gm != 0u) {             // P ~ 0.24^4 ~ 0.3%
            #pragma unroll
            for (int t = 4; t < MAXT; ++t) {
                int ti = (int)(rowF[13 * J + t] * fnn);
                ti = ti < 0 ? 0 : ti;
                ti = ti > nn - 1 ? nn - 1 : ti;
                bits |= ((gm >> ti) & 1u) << t;
            }
        }
        const int nt = bits ? __ffs(bits) : MAXT;     // num_trials
        const float wt = (nt == 1) ? H14 : (nt == 2) ? H7
                       : (nt == 3) ? H5  : (nt == 4) ? H4
                       : (nt <= 6) ? H3  : H2;        // L[13 // nt]
        lw += wt * nsum;
    }
}

// 2 waves per 64-row group: half 0 = even labels + kappa, half 1 = odd labels.
// Doubles resident waves (8192 total = 32/CU at <=64 VGPR) for latency hiding.
__global__ __launch_bounds__(TPB, 8) void rwl_kernel(
    const float* __restrict__ inp, const int* __restrict__ target,
    const float* __restrict__ S, const float* __restrict__ rand_u,
    float* __restrict__ out, int B)
{
    __shared__ float s_red[4];
    const int tid  = threadIdx.x;
    const int lane = tid & 63;
    const int wid  = tid >> 6;
    const int row  = blockIdx.x * 128 + ((wid >> 1) << 6) + lane;
    const int half = __builtin_amdgcn_readfirstlane(wid & 1);  // wave-uniform

    float total = 0.f;
    if (row < B) {
        const float* xp = inp    + (size_t)row * CC;
        const int*   tp = target + (size_t)row * CC;

        float4u xv0 = *(const float4u*)(xp);
        float4u xv1 = *(const float4u*)(xp + 4);
        float4u xv2 = *(const float4u*)(xp + 8);
        float2u xv3 = *(const float2u*)(xp + 12);
        int4u   tv0 = *(const int4u*)(tp);
        int4u   tv1 = *(const int4u*)(tp + 4);
        int4u   tv2 = *(const int4u*)(tp + 8);
        int2u   tv3 = *(const int2u*)(tp + 12);

        const float x[CC] = {xv0.x,xv0.y,xv0.z,xv0.w, xv1.x,xv1.y,xv1.z,xv1.w,
                             xv2.x,xv2.y,xv2.z,xv2.w, xv3.x,xv3.y};
        const int  tg[CC] = {tv0.x,tv0.y,tv0.z,tv0.w, tv1.x,tv1.y,tv1.z,tv1.w,
                             tv2.x,tv2.y,tv2.z,tv2.w, tv3.x,tv3.y};

        unsigned pm = 0; float kap = 0.f;
        #pragma unroll
        for (int k = 0; k < CC; ++k) {
            if (tg[k] != 0) {
                pm |= (1u << k);
                kap += fminf(fmaxf(1.0f - x[k], 0.f), RAMP_CAP);
            } else {
                kap += 1.0f;                 // clip(1 - 0*x, 0, 1.8) = 1
            }
        }
        const int nn = CC - __popc(pm);

        float lw = 0.f;
        if (pm != 0u && nn > 0) {
            const float fnn = (float)nn;
            const float* rowF = rand_u + (size_t)row * (CC * MAXT);
            if (half == 0) {                 // scalar branch (wave-uniform)
                do_label< 0>(pm, nn, fnn, rowF, x, lw);
                do_label< 2>(pm, nn, fnn, rowF, x, lw);
                do_label< 4>(pm, nn, fnn, rowF, x, lw);
                do_label< 6>(pm, nn, fnn, rowF, x, lw);
                do_label< 8>(pm, nn, fnn, rowF, x, lw);
                do_label<10>(pm, nn, fnn, rowF, x, lw);
                do_label<12>(pm, nn, fnn, rowF, x, lw);
            } else {
                do_label< 1>(pm, nn, fnn, rowF, x, lw);
                do_label< 3>(pm, nn, fnn, rowF, x, lw);
                do_label< 5>(pm, nn, fnn, rowF, x, lw);
                do_label< 7>(pm, nn, fnn, rowF, x, lw);
                do_label< 9>(pm, nn, fnn, rowF, x, lw);
                do_label<11>(pm, nn, fnn, rowF, x, lw);
                do_label<13>(pm, nn, fnn, rowF, x, lw);
            }
        }
        float v = lw;
        if (half == 0) v += 2.0f * kap;      // kappa counted once per row
        const float si = (row <= 14) ? 1.0f : S[row - 14];
        total = si * v;
    }

    // block reduction: wave shuffle, LDS across 4 waves, 1 atomic per block
    #pragma unroll
    for (int off = 32; off > 0; off >>= 1)
        total += __shfl_down(total, off, 64);
    if ((tid & 63) == 0) s_red[wid] = total;
    __syncthreads();
    if (tid == 0)
        atomicAdd(out, s_red[0] + s_red[1] + s_red[2] + s_red[3]);
}

extern "C" void kernel_launch(void* const* d_in, const int* in_sizes, int n_in,
                              void* d_out, int out_size, void* d_ws, size_t ws_size,
                              hipStream_t stream) {
    const float* inp    = (const float*)d_in[0];
    const int*   target = (const int*)d_in[1];
    const float* S      = (const float*)d_in[2];
    const float* ru     = (const float*)d_in[3];
    float*       out    = (float*)d_out;
    const int B = in_sizes[2];   // S has B elements

    // d_out is poisoned and not re-zeroed between replays: zero it each call
    hipMemsetAsync(out, 0, sizeof(float), stream);

    const int blocks = (B + 127) / 128;   // 2 waves per 64-row group
    rwl_kernel<<<blocks, TPB, 0, stream>>>(inp, target, S, ru, out, B);
}

// Round 11
// 58.916 us; speedup vs baseline: 1.0078x; 1.0078x over previous
//
#include <hip/hip_runtime.h>

#define CC   14      // num labels
#define MAXT 13      // max trials
#define TPB  256     // one row per thread
#define RAMP_CAP 1.8f

// harmonic numbers, fp32 chain in reference cumsum order
constexpr float H2  = 1.0f + 0.5f;
constexpr float H3  = H2  + (1.0f/3.0f);
constexpr float H4  = H3  + 0.25f;
constexpr float H5  = H4  + 0.2f;
constexpr float H6  = H5  + (1.0f/6.0f);
constexpr float H7  = H6  + (1.0f/7.0f);
constexpr float H14 = H7 + 0.125f + (1.0f/9.0f) + 0.1f + (1.0f/11.0f)
                         + (1.0f/12.0f) + (1.0f/13.0f) + (1.0f/14.0f);

// 4B-aligned vector types: legal on gfx9; a 16B load at float index 13*j
// (byte 52*j) never crosses a 128B line (52j mod 128 <= 112 for j in 0..13).
typedef float float4u __attribute__((ext_vector_type(4), aligned(4)));
typedef float float2u __attribute__((ext_vector_type(2), aligned(4)));
typedef int   int4u   __attribute__((ext_vector_type(4), aligned(4)));
typedef int   int2u   __attribute__((ext_vector_type(2), aligned(4)));

// Compute for one label from a PRE-LOADED trial quad (no load inside guard;
// only the ~0.3% tail path touches memory, gated by gm!=0 = resolvable).
template<int J>
__device__ __forceinline__ void do_label(unsigned pm, int nn, float fnn,
                                         const float4u (&q)[CC],
                                         const float* __restrict__ rowF,
                                         const float (&x)[CC], float& lw)
{
    if ((pm >> J) & 1u) {
        const float e[4] = {q[J].x, q[J].y, q[J].z, q[J].w};

        // one pass over row: neg_sum + resolving-negative bitmask (k-order)
        const float m1 = 1.0f - x[J];
        float nsum = 0.f; unsigned gm = 0; int cnt = 0;
        #pragma unroll
        for (int k = 0; k < CC; ++k) {
            if (!((pm >> k) & 1u)) {
                nsum += fminf(fmaxf(x[J] - x[k], 0.f), RAMP_CAP);
                if (m1 + x[k] >= 0.f) gm |= (1u << cnt);   // ref association
                ++cnt;
            }
        }

        unsigned bits = 0;
        #pragma unroll
        for (int t = 0; t < 4; ++t) {
            int ti = (int)(e[t] * fnn);           // trunc == astype(int32)
            ti = ti < 0 ? 0 : ti;
            ti = ti > nn - 1 ? nn - 1 : ti;
            bits |= ((gm >> ti) & 1u) << t;
        }
        if (bits == 0u && gm != 0u) {             // P ~ 0.24^4 ~ 0.3%
            #pragma unroll
            for (int t = 4; t < MAXT; ++t) {
                int ti = (int)(rowF[13 * J + t] * fnn);
                ti = ti < 0 ? 0 : ti;
                ti = ti > nn - 1 ? nn - 1 : ti;
                bits |= ((gm >> ti) & 1u) << t;
            }
        }
        const int nt = bits ? __ffs(bits) : MAXT;     // num_trials
        const float wt = (nt == 1) ? H14 : (nt == 2) ? H7
                       : (nt == 3) ? H5  : (nt == 4) ? H4
                       : (nt <= 6) ? H3  : H2;        // L[13 // nt]
        lw += wt * nsum;
    }
}

__global__ __launch_bounds__(TPB, 4) void rwl_kernel(
    const float* __restrict__ inp, const int* __restrict__ target,
    const float* __restrict__ S, const float* __restrict__ rand_u,
    float* __restrict__ out, int B)
{
    __shared__ float s_red[4];
    const int tid = threadIdx.x;
    const int row = blockIdx.x * TPB + tid;

    float total = 0.f;
    if (row < B) {
        const float* xp   = inp    + (size_t)row * CC;
        const int*   tp   = target + (size_t)row * CC;
        const float* rowF = rand_u + (size_t)row * (CC * MAXT);

        // ---- issue ALL loads up-front, unguarded: 16 independent in flight,
        //      ONE latency drain instead of ~7 serial guarded hops ----
        float4u xv0 = *(const float4u*)(xp);
        float4u xv1 = *(const float4u*)(xp + 4);
        float4u xv2 = *(const float4u*)(xp + 8);
        float2u xv3 = *(const float2u*)(xp + 12);
        int4u   tv0 = *(const int4u*)(tp);
        int4u   tv1 = *(const int4u*)(tp + 4);
        int4u   tv2 = *(const int4u*)(tp + 8);
        int2u   tv3 = *(const int2u*)(tp + 12);

        float4u q[CC];                       // trials 0..3 for every label
        #pragma unroll
        for (int j = 0; j < CC; ++j)
            q[j] = *(const float4u*)(rowF + 13 * j);

        const float x[CC] = {xv0.x,xv0.y,xv0.z,xv0.w, xv1.x,xv1.y,xv1.z,xv1.w,
                             xv2.x,xv2.y,xv2.z,xv2.w, xv3.x,xv3.y};
        const int  tg[CC] = {tv0.x,tv0.y,tv0.z,tv0.w, tv1.x,tv1.y,tv1.z,tv1.w,
                             tv2.x,tv2.y,tv2.z,tv2.w, tv3.x,tv3.y};

        unsigned pm = 0; float kap = 0.f;
        #pragma unroll
        for (int k = 0; k < CC; ++k) {
            if (tg[k] != 0) {
                pm |= (1u << k);
                kap += fminf(fmaxf(1.0f - x[k], 0.f), RAMP_CAP);
            } else {
                kap += 1.0f;                 // clip(1 - 0*x, 0, 1.8) = 1
            }
        }
        const int nn = CC - __popc(pm);

        float lw = 0.f;
        if (pm != 0u && nn > 0) {
            const float fnn = (float)nn;
            do_label< 0>(pm, nn, fnn, q, rowF, x, lw);
            do_label< 1>(pm, nn, fnn, q, rowF, x, lw);
            do_label< 2>(pm, nn, fnn, q, rowF, x, lw);
            do_label< 3>(pm, nn, fnn, q, rowF, x, lw);
            do_label< 4>(pm, nn, fnn, q, rowF, x, lw);
            do_label< 5>(pm, nn, fnn, q, rowF, x, lw);
            do_label< 6>(pm, nn, fnn, q, rowF, x, lw);
            do_label< 7>(pm, nn, fnn, q, rowF, x, lw);
            do_label< 8>(pm, nn, fnn, q, rowF, x, lw);
            do_label< 9>(pm, nn, fnn, q, rowF, x, lw);
            do_label<10>(pm, nn, fnn, q, rowF, x, lw);
            do_label<11>(pm, nn, fnn, q, rowF, x, lw);
            do_label<12>(pm, nn, fnn, q, rowF, x, lw);
            do_label<13>(pm, nn, fnn, q, rowF, x, lw);
        }
        const float si = (row <= 14) ? 1.0f : S[row - 14];
        total = si * (lw + 2.0f * kap);
    }

    // block reduction: wave shuffle, LDS across 4 waves, 1 atomic per block
    #pragma unroll
    for (int off = 32; off > 0; off >>= 1)
        total += __shfl_down(total, off, 64);
    if ((tid & 63) == 0) s_red[tid >> 6] = total;
    __syncthreads();
    if (tid == 0)
        atomicAdd(out, s_red[0] + s_red[1] + s_red[2] + s_red[3]);
}

extern "C" void kernel_launch(void* const* d_in, const int* in_sizes, int n_in,
                              void* d_out, int out_size, void* d_ws, size_t ws_size,
                              hipStream_t stream) {
    const float* inp    = (const float*)d_in[0];
    const int*   target = (const int*)d_in[1];
    const float* S      = (const float*)d_in[2];
    const float* ru     = (const float*)d_in[3];
    float*       out    = (float*)d_out;
    const int B = in_sizes[2];   // S has B elements

    // d_out is poisoned and not re-zeroed between replays: zero it each call
    hipMemsetAsync(out, 0, sizeof(float), stream);

    const int blocks = (B + TPB - 1) / TPB;
    rwl_kernel<<<blocks, TPB, 0, stream>>>(inp, target, S, ru, out, B);
}

// Round 12
// 55.899 us; speedup vs baseline: 1.0622x; 1.0540x over previous
//
#include <hip/hip_runtime.h>

#define CC   14      // num labels
#define MAXT 13      // max trials
#define TPB  256     // one row per thread
#define RAMP_CAP 1.8f

// harmonic numbers, fp32 chain in reference cumsum order
constexpr float H2  = 1.0f + 0.5f;
constexpr float H3  = H2  + (1.0f/3.0f);
constexpr float H4  = H3  + 0.25f;
constexpr float H5  = H4  + 0.2f;
constexpr float H6  = H5  + (1.0f/6.0f);
constexpr float H7  = H6  + (1.0f/7.0f);
constexpr float H14 = H7 + 0.125f + (1.0f/9.0f) + 0.1f + (1.0f/11.0f)
                         + (1.0f/12.0f) + (1.0f/13.0f) + (1.0f/14.0f);

// 4B-aligned vector types: legal on gfx9; a 16B load at float index 13*j
// (byte 52*j) never crosses a 128B line (52j mod 128 <= 112 for j in 0..13).
typedef float float4u __attribute__((ext_vector_type(4), aligned(4)));
typedef float float2u __attribute__((ext_vector_type(2), aligned(4)));
typedef int   int4u   __attribute__((ext_vector_type(4), aligned(4)));
typedef int   int2u   __attribute__((ext_vector_type(2), aligned(4)));

// Compute for one label from a PRE-LOADED trial quad. Pure-register except
// the ~0.3% tail path (gated by gm!=0 = resolvable).
template<int J>
__device__ __forceinline__ void do_label(unsigned pm, int nn, float fnn,
                                         const float4u (&q)[CC],
                                         const float* __restrict__ rowF,
                                         const float (&x)[CC], float& lw)
{
    if ((pm >> J) & 1u) {
        const float e[4] = {q[J].x, q[J].y, q[J].z, q[J].w};

        // one pass over row: neg_sum + resolving-negative bitmask (k-order)
        const float m1 = 1.0f - x[J];
        float nsum = 0.f; unsigned gm = 0; int cnt = 0;
        #pragma unroll
        for (int k = 0; k < CC; ++k) {
            if (!((pm >> k) & 1u)) {
                nsum += fminf(fmaxf(x[J] - x[k], 0.f), RAMP_CAP);
                if (m1 + x[k] >= 0.f) gm |= (1u << cnt);   // ref association
                ++cnt;
            }
        }

        unsigned bits = 0;
        #pragma unroll
        for (int t = 0; t < 4; ++t) {
            int ti = (int)(e[t] * fnn);           // trunc == astype(int32)
            ti = ti < 0 ? 0 : ti;
            ti = ti > nn - 1 ? nn - 1 : ti;
            bits |= ((gm >> ti) & 1u) << t;
        }
        if (bits == 0u && gm != 0u) {             // P ~ 0.24^4 ~ 0.3%
            #pragma unroll
            for (int t = 4; t < MAXT; ++t) {
                int ti = (int)(rowF[13 * J + t] * fnn);
                ti = ti < 0 ? 0 : ti;
                ti = ti > nn - 1 ? nn - 1 : ti;
                bits |= ((gm >> ti) & 1u) << t;
            }
        }
        const int nt = bits ? __ffs(bits) : MAXT;     // num_trials
        const float wt = (nt == 1) ? H14 : (nt == 2) ? H7
                       : (nt == 3) ? H5  : (nt == 4) ? H4
                       : (nt <= 6) ? H3  : H2;        // L[13 // nt]
        lw += wt * nsum;
    }
}

__global__ __launch_bounds__(TPB, 4) void rwl_kernel(
    const float* __restrict__ inp, const int* __restrict__ target,
    const float* __restrict__ S, const float* __restrict__ rand_u,
    float* __restrict__ out, int B)
{
    __shared__ float s_red[4];
    const int tid = threadIdx.x;
    const int row = blockIdx.x * TPB + tid;

    float total = 0.f;
    if (row < B) {
        const float* xp   = inp    + (size_t)row * CC;
        const int*   tp   = target + (size_t)row * CC;
        const float* rowF = rand_u + (size_t)row * (CC * MAXT);

        float4u xv0 = *(const float4u*)(xp);
        float4u xv1 = *(const float4u*)(xp + 4);
        float4u xv2 = *(const float4u*)(xp + 8);
        float2u xv3 = *(const float2u*)(xp + 12);
        int4u   tv0 = *(const int4u*)(tp);
        int4u   tv1 = *(const int4u*)(tp + 4);
        int4u   tv2 = *(const int4u*)(tp + 8);
        int2u   tv3 = *(const int2u*)(tp + 12);

        const float x[CC] = {xv0.x,xv0.y,xv0.z,xv0.w, xv1.x,xv1.y,xv1.z,xv1.w,
                             xv2.x,xv2.y,xv2.z,xv2.w, xv3.x,xv3.y};
        const int  tg[CC] = {tv0.x,tv0.y,tv0.z,tv0.w, tv1.x,tv1.y,tv1.z,tv1.w,
                             tv2.x,tv2.y,tv2.z,tv2.w, tv3.x,tv3.y};

        unsigned pm = 0; float kap = 0.f;
        #pragma unroll
        for (int k = 0; k < CC; ++k) {
            if (tg[k] != 0) {
                pm |= (1u << k);
                kap += fminf(fmaxf(1.0f - x[k], 0.f), RAMP_CAP);
            } else {
                kap += 1.0f;                 // clip(1 - 0*x, 0, 1.8) = 1
            }
        }
        const int nn = CC - __popc(pm);

        // ---- predicated-address loads: 14 UNCONDITIONAL loads (no exec-mask
        // regions -> back-to-back issue, one drain), per-lane address select:
        // negative labels read rowF line 0 (touched anyway, L1-coalesced) ----
        float4u q[CC];
        #pragma unroll
        for (int j = 0; j < CC; ++j) {
            const float* a = ((pm >> j) & 1u) ? (rowF + 13 * j) : rowF;
            q[j] = *(const float4u*)a;
        }

        float lw = 0.f;
        if (pm != 0u && nn > 0) {
            const float fnn = (float)nn;
            do_label< 0>(pm, nn, fnn, q, rowF, x, lw);
            do_label< 1>(pm, nn, fnn, q, rowF, x, lw);
            do_label< 2>(pm, nn, fnn, q, rowF, x, lw);
            do_label< 3>(pm, nn, fnn, q, rowF, x, lw);
            do_label< 4>(pm, nn, fnn, q, rowF, x, lw);
            do_label< 5>(pm, nn, fnn, q, rowF, x, lw);
            do_label< 6>(pm, nn, fnn, q, rowF, x, lw);
            do_label< 7>(pm, nn, fnn, q, rowF, x, lw);
            do_label< 8>(pm, nn, fnn, q, rowF, x, lw);
            do_label< 9>(pm, nn, fnn, q, rowF, x, lw);
            do_label<10>(pm, nn, fnn, q, rowF, x, lw);
            do_label<11>(pm, nn, fnn, q, rowF, x, lw);
            do_label<12>(pm, nn, fnn, q, rowF, x, lw);
            do_label<13>(pm, nn, fnn, q, rowF, x, lw);
        }
        const float si = (row <= 14) ? 1.0f : S[row - 14];
        total = si * (lw + 2.0f * kap);
    }

    // block reduction: wave shuffle, LDS across 4 waves, 1 atomic per block
    #pragma unroll
    for (int off = 32; off > 0; off >>= 1)
        total += __shfl_down(total, off, 64);
    if ((tid & 63) == 0) s_red[tid >> 6] = total;
    __syncthreads();
    if (tid == 0)
        atomicAdd(out, s_red[0] + s_red[1] + s_red[2] + s_red[3]);
}

extern "C" void kernel_launch(void* const* d_in, const int* in_sizes, int n_in,
                              void* d_out, int out_size, void* d_ws, size_t ws_size,
                              hipStream_t stream) {
    const float* inp    = (const float*)d_in[0];
    const int*   target = (const int*)d_in[1];
    const float* S      = (const float*)d_in[2];
    const float* ru     = (const float*)d_in[3];
    float*       out    = (float*)d_out;
    const int B = in_sizes[2];   // S has B elements

    // d_out is poisoned and not re-zeroed between replays: zero it each call
    hipMemsetAsync(out, 0, sizeof(float), stream);

    const int blocks = (B + TPB - 1) / TPB;
    rwl_kernel<<<blocks, TPB, 0, stream>>>(inp, target, S, ru, out, B);
}

// Round 13
// 47.877 us; speedup vs baseline: 1.2402x; 1.1676x over previous
//
#include <hip/hip_runtime.h>

#define CC   14      // num labels
#define MAXT 13      // max trials
#define TPB  256     // one row per thread
#define RAMP_CAP 1.8f

// harmonic numbers, fp32 chain in reference cumsum order
constexpr float H2  = 1.0f + 0.5f;
constexpr float H3  = H2  + (1.0f/3.0f);
constexpr float H4  = H3  + 0.25f;
constexpr float H5  = H4  + 0.2f;
constexpr float H6  = H5  + (1.0f/6.0f);
constexpr float H7  = H6  + (1.0f/7.0f);
constexpr float H14 = H7 + 0.125f + (1.0f/9.0f) + 0.1f + (1.0f/11.0f)
                         + (1.0f/12.0f) + (1.0f/13.0f) + (1.0f/14.0f);

// 4B-aligned vector types: legal for global_load_dwordx4 on gfx9, and a 16B
// load at float index 13*j (byte 52*j) never crosses a 128B line (52j mod 128
// <= 112 for all j in 0..13) -> exactly one line per label's trials 0..3.
typedef float float4u __attribute__((ext_vector_type(4), aligned(4)));
typedef float float2u __attribute__((ext_vector_type(2), aligned(4)));
typedef int   int4u   __attribute__((ext_vector_type(4), aligned(4)));
typedef int   int2u   __attribute__((ext_vector_type(2), aligned(4)));

// One positive label: one unaligned float4 = trials 0..3 (99.67% resolve);
// tail trials 4..12 is a ~0.3% scalar path, gated by gm!=0 (resolvable).
// The exec-mask guard keeps negative lanes' line-requests OFF the TA path —
// measured better than unguarded (R11), predicated-address (R12), wave-split
// (R10), LDS staging (R3), and scalar (R2) variants.
template<int J>
__device__ __forceinline__ void do_label(unsigned pm, int nn, float fnn,
                                         const float* __restrict__ rowF,
                                         const float (&x)[CC], float& lw)
{
    if ((pm >> J) & 1u) {
        const float4u q = *(const float4u*)(rowF + 13 * J);
        const float e[4] = {q.x, q.y, q.z, q.w};

        // one pass over row: neg_sum + resolving-negative bitmask (k-order)
        const float m1 = 1.0f - x[J];
        float nsum = 0.f; unsigned gm = 0; int cnt = 0;
        #pragma unroll
        for (int k = 0; k < CC; ++k) {
            if (!((pm >> k) & 1u)) {
                nsum += fminf(fmaxf(x[J] - x[k], 0.f), RAMP_CAP);
                if (m1 + x[k] >= 0.f) gm |= (1u << cnt);   // ref association
                ++cnt;
            }
        }

        unsigned bits = 0;
        #pragma unroll
        for (int t = 0; t < 4; ++t) {
            int ti = (int)(e[t] * fnn);           // trunc == astype(int32)
            ti = ti < 0 ? 0 : ti;
            ti = ti > nn - 1 ? nn - 1 : ti;
            bits |= ((gm >> ti) & 1u) << t;
        }
        // tail: only when unresolved AND resolvable (gm==0 -> nt stays MAXT)
        if (bits == 0u && gm != 0u) {             // P ~ 0.24^4 ~ 0.3%
            #pragma unroll
            for (int t = 4; t < MAXT; ++t) {
                int ti = (int)(rowF[13 * J + t] * fnn);
                ti = ti < 0 ? 0 : ti;
                ti = ti > nn - 1 ? nn - 1 : ti;
                bits |= ((gm >> ti) & 1u) << t;
            }
        }
        const int nt = bits ? __ffs(bits) : MAXT;     // num_trials
        const float wt = (nt == 1) ? H14 : (nt == 2) ? H7
                       : (nt == 3) ? H5  : (nt == 4) ? H4
                       : (nt <= 6) ? H3  : H2;        // L[13 // nt]
        lw += wt * nsum;
    }
}

__global__ __launch_bounds__(TPB, 4) void rwl_kernel(
    const float* __restrict__ inp, const int* __restrict__ target,
    const float* __restrict__ S, const float* __restrict__ rand_u,
    float* __restrict__ out, int B)
{
    __shared__ float s_red[4];
    const int tid = threadIdx.x;
    const int row = blockIdx.x * TPB + tid;

    float total = 0.f;
    if (row < B) {
        const float* xp = inp    + (size_t)row * CC;
        const int*   tp = target + (size_t)row * CC;

        // row loads: 4B-aligned vector loads, no parity machinery
        float4u xv0 = *(const float4u*)(xp);
        float4u xv1 = *(const float4u*)(xp + 4);
        float4u xv2 = *(const float4u*)(xp + 8);
        float2u xv3 = *(const float2u*)(xp + 12);
        int4u   tv0 = *(const int4u*)(tp);
        int4u   tv1 = *(const int4u*)(tp + 4);
        int4u   tv2 = *(const int4u*)(tp + 8);
        int2u   tv3 = *(const int2u*)(tp + 12);

        const float x[CC] = {xv0.x,xv0.y,xv0.z,xv0.w, xv1.x,xv1.y,xv1.z,xv1.w,
                             xv2.x,xv2.y,xv2.z,xv2.w, xv3.x,xv3.y};
        const int  tg[CC] = {tv0.x,tv0.y,tv0.z,tv0.w, tv1.x,tv1.y,tv1.z,tv1.w,
                             tv2.x,tv2.y,tv2.z,tv2.w, tv3.x,tv3.y};

        unsigned pm = 0; float kap = 0.f;
        #pragma unroll
        for (int k = 0; k < CC; ++k) {
            if (tg[k] != 0) {
                pm |= (1u << k);
                kap += fminf(fmaxf(1.0f - x[k], 0.f), RAMP_CAP);
            } else {
                kap += 1.0f;                 // clip(1 - 0*x, 0, 1.8) = 1
            }
        }
        const int nn = CC - __popc(pm);

        float lw = 0.f;
        if (pm != 0u && nn > 0) {
            const float fnn = (float)nn;
            const float* rowF = rand_u + (size_t)row * (CC * MAXT);
            do_label< 0>(pm, nn, fnn, rowF, x, lw);
            do_label< 1>(pm, nn, fnn, rowF, x, lw);
            do_label< 2>(pm, nn, fnn, rowF, x, lw);
            do_label< 3>(pm, nn, fnn, rowF, x, lw);
            do_label< 4>(pm, nn, fnn, rowF, x, lw);
            do_label< 5>(pm, nn, fnn, rowF, x, lw);
            do_label< 6>(pm, nn, fnn, rowF, x, lw);
            do_label< 7>(pm, nn, fnn, rowF, x, lw);
            do_label< 8>(pm, nn, fnn, rowF, x, lw);
            do_label< 9>(pm, nn, fnn, rowF, x, lw);
            do_label<10>(pm, nn, fnn, rowF, x, lw);
            do_label<11>(pm, nn, fnn, rowF, x, lw);
            do_label<12>(pm, nn, fnn, rowF, x, lw);
            do_label<13>(pm, nn, fnn, rowF, x, lw);
        }
        const float si = (row <= 14) ? 1.0f : S[row - 14];
        total = si * (lw + 2.0f * kap);
    }

    // block reduction: wave shuffle, LDS across 4 waves, 1 atomic per block
    #pragma unroll
    for (int off = 32; off > 0; off >>= 1)
        total += __shfl_down(total, off, 64);
    if ((tid & 63) == 0) s_red[tid >> 6] = total;
    __syncthreads();
    if (tid == 0)
        atomicAdd(out, s_red[0] + s_red[1] + s_red[2] + s_red[3]);
}

extern "C" void kernel_launch(void* const* d_in, const int* in_sizes, int n_in,
                              void* d_out, int out_size, void* d_ws, size_t ws_size,
                              hipStream_t stream) {
    const float* inp    = (const float*)d_in[0];
    const int*   target = (const int*)d_in[1];
    const float* S      = (const float*)d_in[2];
    const float* ru     = (const float*)d_in[3];
    float*       out    = (float*)d_out;
    const int B = in_sizes[2];   // S has B elements

    // d_out is poisoned and not re-zeroed between replays: zero it each call
    hipMemsetAsync(out, 0, sizeof(float), stream);

    const int blocks = (B + TPB - 1) / TPB;
    rwl_kernel<<<blocks, TPB, 0, stream>>>(inp, target, S, ru, out, B);
}